// Round 8
// baseline (238.047 us; speedup 1.0000x reference)
//
#include <hip/hip_runtime.h>
#include <hip/hip_fp16.h>
#include <math.h>

// ---------------------------------------------------------------------------
// VariationalGCNEncoder: N=50000, E=800000, 128 -> 64 -> {32,32}
// R8: - [count | wtbf=bf16(W1^T)] fused micro-kernel
//     - [fill | MFMA gemm] fused (gemm hides under fill's scatter latency;
//       B-fragments from wtbf as b128 loads — R6-proven form)
//     - gather core: wave-uniform full/masked step split (no min/cndmask on
//       the hot path; deg<=64 so one chunk) + float2 pk-fma accumulation
// Pipeline:
//   memset(counts) -> [count | wtbf] -> scan1 -> scan23 -> [fill | gemm]
//   gather1: h = relu(A_norm . h_pre + b1)         (bf16x2)
//   gather2: out = (A_norm . h) @ [Wmu|Wls] + bias (f32)
// ---------------------------------------------------------------------------

typedef unsigned int uint;
typedef unsigned short ushort;
typedef __attribute__((ext_vector_type(8))) short short8;   // 8 bf16 = 4 VGPR
typedef __attribute__((ext_vector_type(4))) float f32x4;    // MFMA acc
typedef __attribute__((ext_vector_type(2))) float f32v2;    // pk-fma pair

__device__ __forceinline__ ushort f2bf(float x) {          // f32 -> bf16 RNE
    uint u = __float_as_uint(x);
    u += 0x7fffu + ((u >> 16) & 1u);
    return (ushort)(u >> 16);
}
__device__ __forceinline__ float bf2f(ushort h) {
    return __uint_as_float((uint)h << 16);
}
__device__ __forceinline__ float unpack_norm(uint r) {     // fp16 in high 16
    return __half2float(__ushort_as_half((ushort)(r >> 16)));
}

// blocks [0,CB): degree count; block CB: W1 -> wtbf[n][k] bf16 (16 KB)
__global__ __launch_bounds__(256) void k_count_w(
        const int* __restrict__ dst, int* __restrict__ counts, int E, int CB,
        const float* __restrict__ W1, ushort* __restrict__ wtbf) {
    const int tid = threadIdx.x;
    if (blockIdx.x < CB) {
        int i = blockIdx.x * 256 + tid;
        if (i < E) atomicAdd(&counts[dst[i]], 1);
        return;
    }
    for (int i = tid; i < 128 * 64; i += 256) {
        int k = i >> 6, n = i & 63;                // W1[k][n], coalesced read
        wtbf[n * 128 + k] = f2bf(W1[i]);
    }
}

// per-block exclusive scan of counts -> row_ptr, block sums -> bsum
__global__ __launch_bounds__(256) void k_scan1(const int* __restrict__ counts,
                                               int* __restrict__ row_ptr,
                                               int* __restrict__ bsum, int N) {
    __shared__ int s[256];
    int t = threadIdx.x, i = blockIdx.x * 256 + t;
    int v = (i < N) ? counts[i] : 0;
    s[t] = v;
    __syncthreads();
    #pragma unroll
    for (int off = 1; off < 256; off <<= 1) {
        int x = (t >= off) ? s[t - off] : 0;
        __syncthreads();
        s[t] += x;
        __syncthreads();
    }
    if (i < N) row_ptr[i] = s[t] - v;
    if (t == 255) bsum[blockIdx.x] = s[255];
}

// fused scan2+scan3 (NB<=256)
__global__ __launch_bounds__(256) void k_scan23(
        int* __restrict__ row_ptr, const int* __restrict__ bsum,
        const int* __restrict__ counts, int* __restrict__ cursor,
        float* __restrict__ dinv, int N, int E, int NB) {
    __shared__ int s[256];
    const int t = threadIdx.x;
    s[t] = (t < blockIdx.x && t < NB) ? bsum[t] : 0;
    __syncthreads();
    #pragma unroll
    for (int off = 128; off >= 1; off >>= 1) {
        if (t < off) s[t] += s[t + off];
        __syncthreads();
    }
    const int offset = s[0];
    const int i = blockIdx.x * 256 + t;
    if (i < N) {
        int r = row_ptr[i] + offset;
        row_ptr[i] = r;
        cursor[i] = r;
        dinv[i] = rsqrtf((float)(counts[i] + 1));
    }
    if (blockIdx.x == 0 && t == 0) row_ptr[N] = E;
}

// blocks [0,FB): CSR fill (packed 4B records); [FB,..): MFMA gemm
// h_pre = bf16(x) @ W1  (A: f32 x, in-register convert; B: wtbf b128 loads)
__global__ __launch_bounds__(256, 8) void k_fill_gemm(
        const int* __restrict__ src, const int* __restrict__ dst,
        const float* __restrict__ dinv, int* __restrict__ cursor,
        uint* __restrict__ edges, int E, int FB,
        const float* __restrict__ x, const ushort* __restrict__ wtbf,
        ushort* __restrict__ h_pre, int N) {
    const int tid = threadIdx.x;
    if (blockIdx.x < FB) {                         // ---- CSR fill ----
        int e = blockIdx.x * 256 + tid;
        if (e >= E) return;
        int s = src[e], d = dst[e];
        int pos = atomicAdd(&cursor[d], 1);
        ushort nb = __half_as_ushort(__float2half(dinv[s] * dinv[d]));
        edges[pos] = (uint)s | ((uint)nb << 16);
        return;
    }
    // ---- MFMA gemm: wave = 16 rows x 64 cols, k=128 in 4 chunks ----
    const int bid = blockIdx.x - FB;
    const int w = tid >> 6, l = tid & 63;
    const int m = l & 15, q = l >> 4;              // q = quad (0..3)
    const int row0 = bid * 64 + w * 16;
    const size_t arow = (size_t)min(row0 + m, N - 1);   // clamp; store guarded
    f32x4 acc0 = {0.f, 0.f, 0.f, 0.f}, acc1 = acc0, acc2 = acc0, acc3 = acc0;
    #pragma unroll
    for (int kc = 0; kc < 4; ++kc) {
        const int kofs = kc * 32 + q * 8;
        const float4* xr = (const float4*)(x + arow * 128 + kofs);
        float4 xa = xr[0], xb = xr[1];
        short8 a;
        a[0] = (short)f2bf(xa.x); a[1] = (short)f2bf(xa.y);
        a[2] = (short)f2bf(xa.z); a[3] = (short)f2bf(xa.w);
        a[4] = (short)f2bf(xb.x); a[5] = (short)f2bf(xb.y);
        a[6] = (short)f2bf(xb.z); a[7] = (short)f2bf(xb.w);
        short8 b0 = *(const short8*)(wtbf + (size_t)(0 * 16 + m) * 128 + kofs);
        short8 b1 = *(const short8*)(wtbf + (size_t)(1 * 16 + m) * 128 + kofs);
        short8 b2 = *(const short8*)(wtbf + (size_t)(2 * 16 + m) * 128 + kofs);
        short8 b3 = *(const short8*)(wtbf + (size_t)(3 * 16 + m) * 128 + kofs);
        acc0 = __builtin_amdgcn_mfma_f32_16x16x32_bf16(a, b0, acc0, 0, 0, 0);
        acc1 = __builtin_amdgcn_mfma_f32_16x16x32_bf16(a, b1, acc1, 0, 0, 0);
        acc2 = __builtin_amdgcn_mfma_f32_16x16x32_bf16(a, b2, acc2, 0, 0, 0);
        acc3 = __builtin_amdgcn_mfma_f32_16x16x32_bf16(a, b3, acc3, 0, 0, 0);
    }
    #pragma unroll
    for (int r = 0; r < 4; ++r) {                  // D: row=q*4+r, col=g*16+m
        int row = row0 + q * 4 + r;
        if (row >= N) continue;
        ushort* hr = h_pre + (size_t)row * 64 + m;
        hr[0]  = f2bf(acc0[r]);
        hr[16] = f2bf(acc1[r]);
        hr[32] = f2bf(acc2[r]);
        hr[48] = f2bf(acc3[r]);
    }
}

// Gather core: 2 edges/step per wave (half-waves, bf16x2 lanes), 8-step
// unroll = 16 edges in flight. Wave-uniform full/masked split: full groups
// skip min/cndmask entirely. acc is f32v2 (pk-fma).
#define GATHER_CORE(HP2)                                                       \
    for (int base = beg; base < end; base += 64) {                             \
        int cnt = end - base; if (cnt > 64) cnt = 64;                          \
        uint mrec = edges[min(base + lane, E - 1)];                            \
        int steps = (cnt + 1) >> 1;                                            \
        for (int t = 0; t < steps; t += 8) {                                   \
            if (2 * t + 16 <= cnt) {      /* edges 2t..2t+15 all valid */      \
                _Pragma("unroll")                                              \
                for (int i = 0; i < 8; ++i) {                                  \
                    uint r = __shfl(mrec, 2 * (t + i) + half);                 \
                    uint v = HP2[(size_t)(r & 0xffffu) * 32 + hl];             \
                    float wn = unpack_norm(r);                                 \
                    f32v2 vf;                                                  \
                    vf.x = __uint_as_float(v << 16);                           \
                    vf.y = __uint_as_float(v & 0xffff0000u);                   \
                    acc = vf * wn + acc;                                       \
                }                                                              \
            } else {                                                           \
                _Pragma("unroll")                                              \
                for (int i = 0; i < 8; ++i) {                                  \
                    int e = 2 * (t + i) + half;                                \
                    uint r = __shfl(mrec, min(e, cnt - 1));                    \
                    uint v = HP2[(size_t)(r & 0xffffu) * 32 + hl];             \
                    float wn = (e < cnt) ? unpack_norm(r) : 0.f;               \
                    f32v2 vf;                                                  \
                    vf.x = __uint_as_float(v << 16);                           \
                    vf.y = __uint_as_float(v & 0xffff0000u);                   \
                    acc = vf * wn + acc;                                       \
                }                                                              \
            }                                                                  \
        }                                                                      \
    }                                                                          \
    acc.x += __shfl_xor(acc.x, 32);                                            \
    acc.y += __shfl_xor(acc.y, 32);

// h[n,2hl..2hl+1] = relu( dinv^2*h_pre + b1 + sum norm*h_pre[src] )  (bf16x2)
__global__ __launch_bounds__(256, 8) void k_gather1(
        const uint* __restrict__ hp2, const int* __restrict__ row_ptr,
        const uint* __restrict__ edges, const float* __restrict__ dinv,
        const float* __restrict__ b1, uint* __restrict__ ho2, int N, int E) {
    const int lane = threadIdx.x & 63;
    const int hl = lane & 31, half = lane >> 5;
    const int n = blockIdx.x * 4 + (threadIdx.x >> 6);
    if (n >= N) return;
    const int beg = row_ptr[n], end = row_ptr[n + 1];
    f32v2 acc = {0.f, 0.f};
    if (half == 0) {
        uint sv = hp2[(size_t)n * 32 + hl];
        float dv = dinv[n];
        float2 b = ((const float2*)b1)[hl];
        acc.x = dv * dv * bf2f((ushort)sv) + b.x;
        acc.y = dv * dv * bf2f((ushort)(sv >> 16)) + b.y;
    }
    GATHER_CORE(hp2)
    if (half == 0) {
        uint p = (uint)f2bf(fmaxf(acc.x, 0.f)) | ((uint)f2bf(fmaxf(acc.y, 0.f)) << 16);
        ho2[(size_t)n * 32 + hl] = p;
    }
}

// g = A_norm . h;  out[n,col] = sum_k g[k]*W[k][col] + bias (mu | logstd)
__global__ __launch_bounds__(256, 8) void k_gather2(
        const uint* __restrict__ hp2, const int* __restrict__ row_ptr,
        const uint* __restrict__ edges, const float* __restrict__ dinv,
        const float* __restrict__ Wmu, const float* __restrict__ Wls,
        const float* __restrict__ bmu, const float* __restrict__ bls,
        float* __restrict__ out, int N, int E) {
    __shared__ float hs[4][64];    // per-wave gathered row (1 KB)
    const int lane = threadIdx.x & 63;
    const int hl = lane & 31, half = lane >> 5;
    const int w = threadIdx.x >> 6;
    const int n = blockIdx.x * 4 + w;
    if (n >= N) return;
    const int beg = row_ptr[n], end = row_ptr[n + 1];
    f32v2 acc = {0.f, 0.f};
    if (half == 0) {
        uint sv = hp2[(size_t)n * 32 + hl];
        float dv = dinv[n];
        acc.x = dv * dv * bf2f((ushort)sv);
        acc.y = dv * dv * bf2f((ushort)(sv >> 16));
    }
    GATHER_CORE(hp2)
    if (half == 0) {
        float2 p; p.x = acc.x; p.y = acc.y;
        *(float2*)&hs[w][2 * hl] = p;          // g[2hl], g[2hl+1]
    }
    // epilogue: out_row = g @ [Wmu|Wls] + bias ; W from global (L1-hot)
    const float* Wsel = (lane < 32) ? (Wmu + lane) : (Wls + (lane - 32));
    const float bias  = (lane < 32) ? bmu[lane] : bls[lane - 32];
    float c0 = 0.f, c1 = 0.f, c2 = 0.f, c3 = 0.f;
    #pragma unroll 4
    for (int k = 0; k < 64; k += 4) {
        c0 = fmaf(hs[w][k + 0], Wsel[(k + 0) * 32], c0);
        c1 = fmaf(hs[w][k + 1], Wsel[(k + 1) * 32], c1);
        c2 = fmaf(hs[w][k + 2], Wsel[(k + 2) * 32], c2);
        c3 = fmaf(hs[w][k + 3], Wsel[(k + 3) * 32], c3);
    }
    float t = (c0 + c1) + (c2 + c3) + bias;
    if (lane < 32) out[(size_t)n * 32 + lane] = t;
    else           out[(size_t)N * 32 + (size_t)n * 32 + (lane - 32)] = t;
}

extern "C" void kernel_launch(void* const* d_in, const int* in_sizes, int n_in,
                              void* d_out, int out_size, void* d_ws, size_t ws_size,
                              hipStream_t stream) {
    const float* x   = (const float*)d_in[0];
    const int*   ei  = (const int*)d_in[1];
    const float* W1  = (const float*)d_in[2];
    const float* b1  = (const float*)d_in[3];
    const float* Wmu = (const float*)d_in[4];
    const float* bmu = (const float*)d_in[5];
    const float* Wls = (const float*)d_in[6];
    const float* bls = (const float*)d_in[7];
    float* out = (float*)d_out;

    const int N = in_sizes[0] / 128;          // 50000  (< 65536: u16 src pack)
    const int E = in_sizes[1] / 2;            // 800000
    const int* src = ei;
    const int* dst = ei + E;
    const int NB = (N + 255) / 256;           // scan blocks (196 <= 256)
    const int CB = (E + 255) / 256;           // count / fill blocks
    const int GB = (N + 63) / 64;             // gemm row-tile blocks

    char* w = (char*)d_ws;
    auto carve = [&](size_t bytes) { char* p = w; w += (bytes + 1023) & ~(size_t)1023; return p; };
    int*    counts  = (int*)   carve((size_t)N * 4);
    int*    row_ptr = (int*)   carve((size_t)(N + 1) * 4);
    int*    cursor  = (int*)   carve((size_t)N * 4);
    int*    bsum    = (int*)   carve(256 * 4);
    float*  dinv    = (float*) carve((size_t)N * 4);
    uint*   edges   = (uint*)  carve((size_t)E * 4);
    ushort* wtbf    = (ushort*)carve((size_t)64 * 128 * 2); // bf16 W1^T
    ushort* h_pre   = (ushort*)carve((size_t)N * 64 * 2);   // bf16
    ushort* h_mid   = (ushort*)carve((size_t)N * 64 * 2);   // bf16

    hipMemsetAsync(counts, 0, (size_t)N * 4, stream);
    k_count_w  <<<CB + 1, 256, 0, stream>>>(dst, counts, E, CB, W1, wtbf);
    k_scan1    <<<NB, 256, 0, stream>>>(counts, row_ptr, bsum, N);
    k_scan23   <<<NB, 256, 0, stream>>>(row_ptr, bsum, counts, cursor, dinv, N, E, NB);
    k_fill_gemm<<<CB + GB, 256, 0, stream>>>(src, dst, dinv, cursor, edges, E, CB,
                                             x, wtbf, h_pre, N);
    k_gather1  <<<(N + 3) / 4, 256, 0, stream>>>((const uint*)h_pre, row_ptr, edges,
                                                 dinv, b1, (uint*)h_mid, N, E);
    k_gather2  <<<(N + 3) / 4, 256, 0, stream>>>((const uint*)h_mid, row_ptr, edges,
                                                 dinv, Wmu, Wls, bmu, bls, out, N, E);
}